// Round 5
// baseline (500.818 us; speedup 1.0000x reference)
//
#include <hip/hip_runtime.h>
#include <hip/hip_fp16.h>
#include <hip/hip_cooperative_groups.h>

namespace cg = cooperative_groups;

#define N_PTS 100000
#define KSZ 9
#define C_IN 24
#define C_HID 144
#define C_OUT 24
#define G4_HID 36   // C_HID/4
#define G8_HID 18   // C_HID/8
#define G4_OUT 6    // C_OUT/4
#define EPSV 1e-5f

// ---- workspace layout ----
// x1h fp16 (N+1)*144 | x2h fp16 N*144 | y3 f32 N*24 | stats f32 (1024)
#define X2H_B     28800288                    // byte offset of x2h
#define Y3F_O     14400072                    // float index of y3
#define ST_O      16800072                    // float index of stats
#define MU1_O     (ST_O + 0)      // 24
#define M1_O      (ST_O + 32)     // 576
#define SUM2_O    (ST_O + 640)    // 144
#define SQ2_O     (ST_O + 800)    // 144
#define SUM3_O    (ST_O + 960)    // 24
#define SQ3_O     (ST_O + 992)    // 24

__device__ inline float4 f4z() { return make_float4(0.f, 0.f, 0.f, 0.f); }
__device__ inline float4 f4_add(float4 a, float4 b) {
    return make_float4(a.x + b.x, a.y + b.y, a.z + b.z, a.w + b.w);
}
__device__ inline float4 f4_fma4(float4 a, float4 b, float4 c) {
    return make_float4(fmaf(a.x, b.x, c.x), fmaf(a.y, b.y, c.y),
                       fmaf(a.z, b.z, c.z), fmaf(a.w, b.w, c.w));
}
__device__ inline float4 f4_fma_s(float s, float4 b, float4 c) {
    return make_float4(fmaf(s, b.x, c.x), fmaf(s, b.y, c.y),
                       fmaf(s, b.z, c.z), fmaf(s, b.w, c.w));
}
__device__ inline float4 f4_clamp6(float4 a) {
    return make_float4(fminf(fmaxf(a.x, 0.f), 6.f), fminf(fmaxf(a.y, 0.f), 6.f),
                       fminf(fmaxf(a.z, 0.f), 6.f), fminf(fmaxf(a.w, 0.f), 6.f));
}
__device__ inline unsigned pack2(float a, float b) {
    __half2 h = __floats2half2_rn(a, b);
    return *reinterpret_cast<unsigned*>(&h);
}
__device__ inline float2 uph(unsigned u) {
    __half2 h = *reinterpret_cast<__half2*>(&u);
    return __half22float2(h);
}

#define MROWS 128
__device__ inline float task_acc(const float* tile, int cnt, int task) {
    if (task < 576) {
        int i = task / 24, j = task % 24;
        float a = 0.f;
        for (int r = 0; r < cnt; r++) a += tile[r * 24 + i] * tile[r * 24 + j];
        return a;
    }
    int k = task - 576;
    float a = 0.f;
    for (int r = 0; r < cnt; r++) a += tile[r * 24 + k];
    return a;
}

// Single cooperative kernel: phases separated by grid.sync().
// Shared union max user: gemm2 phase = 33,856 B -> 4 blocks/CU (LDS-limited).
__global__ __launch_bounds__(256, 4) void k_fused(
    const float* __restrict__ feats, const float* __restrict__ w1,
    const float* __restrict__ g1, const float* __restrict__ b1,
    const float* __restrict__ w2, const float* __restrict__ g2,
    const float* __restrict__ b2, const float* __restrict__ w3,
    const float* __restrict__ g3, const float* __restrict__ b3,
    const int* __restrict__ in_idx, float* __restrict__ ws,
    float* __restrict__ out) {
    __shared__ __align__(16) char smem[33920];
    cg::grid_group gg = cg::this_grid();
    const int t = threadIdx.x;
    const int bid = blockIdx.x;
    const int nB = gridDim.x;

    // ---- phase 0: zero stat accumulators + fp16 sentinel row ----
    if (bid == 0) {
        for (int i = t; i < 1024; i += 256) ws[ST_O + i] = 0.f;
        if (t < G8_HID) {
            uint4 z; z.x = 0u; z.y = 0u; z.z = 0u; z.w = 0u;
            ((uint4*)ws)[(size_t)N_PTS * G8_HID + t] = z;
        }
    }
    gg.sync();

    // ---- phase 1: feats moments MU1[24], M1[24x24] ----
    {
        float* tile = (float*)smem;  // 12288 B
        float acc0 = 0.f, acc1 = 0.f, acc2 = 0.f;
        const int nChunks = (N_PTS + MROWS - 1) / MROWS;
        for (int ch = bid; ch < nChunks; ch += nB) {
            int r0 = ch * MROWS;
            int cnt = min(MROWS, N_PTS - r0);
            __syncthreads();
            for (int e = t; e < cnt * C_IN; e += 256)
                tile[e] = feats[(size_t)r0 * C_IN + e];
            __syncthreads();
            acc0 += task_acc(tile, cnt, t);
            acc1 += task_acc(tile, cnt, t + 256);
            if (t < 88) acc2 += task_acc(tile, cnt, t + 512);
        }
        if (bid < nChunks) {
            atomicAdd(&ws[M1_O + t], acc0);
            atomicAdd(&ws[M1_O + t + 256], acc1);
            if (t < 88) {
                int task = t + 512;
                if (task < 576) atomicAdd(&ws[M1_O + task], acc2);
                else            atomicAdd(&ws[MU1_O + task - 576], acc2);
            }
        }
    }
    gg.sync();

    // ---- phase 2: GEMM1 + closed-form BN1 + relu6 -> x1h (fp16) ----
    {
        float4* w1s = (float4*)smem;               // 13824 B (3456 f)
        float*  M1s = (float*)(smem + 13824);      // 2304 B
        float*  MU1s = (float*)(smem + 16128);     // 96 B
        float*  scf = (float*)(smem + 16224);      // 576 B (16B aligned)
        float*  shf = (float*)(smem + 16800);      // 576 B
        for (int e = t; e < C_IN * G4_HID; e += 256) w1s[e] = ((const float4*)w1)[e];
        for (int e = t; e < 576; e += 256) M1s[e] = ws[M1_O + e];
        if (t < 24) MU1s[t] = ws[MU1_O + t];
        __syncthreads();
        if (t < C_HID) {
            const float* w1f = (const float*)w1s;
            float wc[C_IN];
#pragma unroll
            for (int k = 0; k < C_IN; k++) wc[k] = w1f[k * C_HID + t];
            const float invN = 1.f / (float)N_PTS;
            float mean = 0.f;
#pragma unroll
            for (int k = 0; k < C_IN; k++) mean += MU1s[k] * wc[k];
            mean *= invN;
            float e2 = 0.f;
            for (int i = 0; i < C_IN; i++) {
                float s = 0.f;
#pragma unroll
                for (int j = 0; j < C_IN; j++) s += M1s[i * 24 + j] * wc[j];
                e2 += wc[i] * s;
            }
            e2 *= invN;
            float var = e2 - mean * mean;
            float s1 = g1[t] * rsqrtf(var + EPSV);
            scf[t] = s1;
            shf[t] = b1[t] - mean * s1;
        }
        __syncthreads();
        const float4* sc4 = (const float4*)scf;
        const float4* sh4 = (const float4*)shf;
        uint4* x1u = (uint4*)ws;
        const int T = N_PTS * G8_HID;
        for (int tau = bid * 256 + t; tau < T; tau += nB * 256) {
            int p = tau / G8_HID;
            int g = tau % G8_HID;
            const float4* fr = (const float4*)(feats + (size_t)p * C_IN);
            float4 a0 = f4z(), a1 = f4z();
#pragma unroll
            for (int q = 0; q < 6; q++) {
                float4 fq = fr[q];
                a0 = f4_fma_s(fq.x, w1s[(4 * q + 0) * G4_HID + 2 * g], a0);
                a1 = f4_fma_s(fq.x, w1s[(4 * q + 0) * G4_HID + 2 * g + 1], a1);
                a0 = f4_fma_s(fq.y, w1s[(4 * q + 1) * G4_HID + 2 * g], a0);
                a1 = f4_fma_s(fq.y, w1s[(4 * q + 1) * G4_HID + 2 * g + 1], a1);
                a0 = f4_fma_s(fq.z, w1s[(4 * q + 2) * G4_HID + 2 * g], a0);
                a1 = f4_fma_s(fq.z, w1s[(4 * q + 2) * G4_HID + 2 * g + 1], a1);
                a0 = f4_fma_s(fq.w, w1s[(4 * q + 3) * G4_HID + 2 * g], a0);
                a1 = f4_fma_s(fq.w, w1s[(4 * q + 3) * G4_HID + 2 * g + 1], a1);
            }
            a0 = f4_clamp6(f4_fma4(a0, sc4[2 * g], sh4[2 * g]));
            a1 = f4_clamp6(f4_fma4(a1, sc4[2 * g + 1], sh4[2 * g + 1]));
            uint4 o;
            o.x = pack2(a0.x, a0.y); o.y = pack2(a0.z, a0.w);
            o.z = pack2(a1.x, a1.y); o.w = pack2(a1.z, a1.w);
            x1u[tau] = o;
        }
    }
    gg.sync();

    // ---- phase 3: channelwise 3x3 conv (fp16 gather) + BN2 stats ----
    // weights in REGISTERS: occupancy is LDS-pinned at 4 blocks/CU, so the
    // ~72 extra VGPRs are free here (R3's occupancy penalty doesn't apply),
    // and the R4 LDS broadcast conflicts (2.7M) disappear.
    {
        float* lsum = (float*)smem;            // 576 B
        float* lsq  = (float*)(smem + 576);    // 576 B
        if (t < C_HID) { lsum[t] = 0.f; lsq[t] = 0.f; }
        __syncthreads();
        const uint4* x1u = (const uint4*)ws;
        uint4* x2u = (uint4*)((char*)ws + X2H_B);
        bool active = t < 252;
        int pt = t / G8_HID, g = t % G8_HID;   // 14 points x 18 lane-groups
        const float4* w2v = (const float4*)w2;
        float4 wA[KSZ], wB[KSZ];
#pragma unroll
        for (int k = 0; k < KSZ; k++) {
            wA[k] = w2v[k * G4_HID + 2 * g];
            wB[k] = w2v[k * G4_HID + 2 * g + 1];
        }
        float4 rsA = f4z(), rsB = f4z(), rqA = f4z(), rqB = f4z();
        const int nChunks = (N_PTS + 13) / 14;
        for (int ch = bid; ch < nChunks; ch += nB) {
            int p = ch * 14 + pt;
            if (active && p < N_PTS) {
                int idx[KSZ];
#pragma unroll
                for (int k = 0; k < KSZ; k++) idx[k] = in_idx[k * N_PTS + p];
                float4 aA = f4z(), aB = f4z();
#pragma unroll
                for (int k = 0; k < KSZ; k++) {
                    uint4 v = x1u[(size_t)idx[k] * G8_HID + g];  // idx==N -> sentinel
                    float2 f0 = uph(v.x), f1 = uph(v.y), f2 = uph(v.z), f3 = uph(v.w);
                    aA = f4_fma4(wA[k], make_float4(f0.x, f0.y, f1.x, f1.y), aA);
                    aB = f4_fma4(wB[k], make_float4(f2.x, f2.y, f3.x, f3.y), aB);
                }
                uint4 o;
                o.x = pack2(aA.x, aA.y); o.y = pack2(aA.z, aA.w);
                o.z = pack2(aB.x, aB.y); o.w = pack2(aB.z, aB.w);
                x2u[(size_t)p * G8_HID + g] = o;
                rsA = f4_add(rsA, aA); rsB = f4_add(rsB, aB);
                rqA = f4_fma4(aA, aA, rqA); rqB = f4_fma4(aB, aB, rqB);
            }
        }
        if (active) {
            int c0 = 8 * g;
            atomicAdd(&lsum[c0 + 0], rsA.x); atomicAdd(&lsum[c0 + 1], rsA.y);
            atomicAdd(&lsum[c0 + 2], rsA.z); atomicAdd(&lsum[c0 + 3], rsA.w);
            atomicAdd(&lsum[c0 + 4], rsB.x); atomicAdd(&lsum[c0 + 5], rsB.y);
            atomicAdd(&lsum[c0 + 6], rsB.z); atomicAdd(&lsum[c0 + 7], rsB.w);
            atomicAdd(&lsq[c0 + 0], rqA.x);  atomicAdd(&lsq[c0 + 1], rqA.y);
            atomicAdd(&lsq[c0 + 2], rqA.z);  atomicAdd(&lsq[c0 + 3], rqA.w);
            atomicAdd(&lsq[c0 + 4], rqB.x);  atomicAdd(&lsq[c0 + 5], rqB.y);
            atomicAdd(&lsq[c0 + 6], rqB.z);  atomicAdd(&lsq[c0 + 7], rqB.w);
        }
        __syncthreads();
        if (t < C_HID) {
            atomicAdd(&ws[SUM2_O + t], lsum[t]);
            atomicAdd(&ws[SQ2_O + t], lsq[t]);
        }
    }
    gg.sync();

    // ---- phase 4: GEMM2 (BN2+relu6 on the fly) -> y3 f32 + BN3 stats ----
    {
        float*   w3s  = (float*)smem;               // 13824 B
        float*   sc2s = (float*)(smem + 13824);     // 576 B
        float*   sh2s = (float*)(smem + 14400);     // 576 B
        float*   ssum = (float*)(smem + 14976);     // 96 B
        float*   ssq  = (float*)(smem + 15072);     // 96 B
        __half2* xs2  = (__half2*)(smem + 15168);   // 64*73 half2 = 18688 B
        for (int e = t; e < C_HID * C_OUT / 4; e += 256)
            ((float4*)w3s)[e] = ((const float4*)w3)[e];
        if (t < C_HID) {
            const float invN = 1.f / (float)N_PTS;
            float mean = ws[SUM2_O + t] * invN;
            float var = ws[SQ2_O + t] * invN - mean * mean;
            float s = g2[t] * rsqrtf(var + EPSV);
            sc2s[t] = s;
            sh2s[t] = b2[t] - mean * s;
        }
        if (t < C_OUT) { ssum[t] = 0.f; ssq[t] = 0.f; }
        __syncthreads();
        const uint4* x2u = (const uint4*)((char*)ws + X2H_B);
        float* y3 = ws + Y3F_O;
        int pl = t & 63, cgid = t >> 6, c0 = 6 * cgid;
        const int nTiles = (N_PTS + 63) / 64;
        for (int tile = bid; tile < nTiles; tile += nB) {
            int p0 = tile * 64;
            for (int e = t; e < 64 * G8_HID; e += 256) {
                int row = e / G8_HID, col = e % G8_HID;
                int p = p0 + row;
                float v[8];
                if (p < N_PTS) {
                    uint4 u = x2u[(size_t)p * G8_HID + col];
                    float2 f0 = uph(u.x), f1 = uph(u.y), f2 = uph(u.z), f3 = uph(u.w);
                    v[0] = f0.x; v[1] = f0.y; v[2] = f1.x; v[3] = f1.y;
                    v[4] = f2.x; v[5] = f2.y; v[6] = f3.x; v[7] = f3.y;
                    int cb = 8 * col;
#pragma unroll
                    for (int i = 0; i < 8; i++)
                        v[i] = fminf(fmaxf(fmaf(v[i], sc2s[cb + i], sh2s[cb + i]), 0.f), 6.f);
                } else {
#pragma unroll
                    for (int i = 0; i < 8; i++) v[i] = 0.f;
                }
                int base = row * 73 + col * 4;   // half2 units; row stride 146 halves
                xs2[base + 0] = __floats2half2_rn(v[0], v[1]);
                xs2[base + 1] = __floats2half2_rn(v[2], v[3]);
                xs2[base + 2] = __floats2half2_rn(v[4], v[5]);
                xs2[base + 3] = __floats2half2_rn(v[6], v[7]);
            }
            __syncthreads();
            float acc[6] = {0.f, 0.f, 0.f, 0.f, 0.f, 0.f};
            const __half2* xr = xs2 + pl * 73;
#pragma unroll 8
            for (int hh = 0; hh < 72; hh++) {
                float2 xv = __half22float2(xr[hh]);
                int h = 2 * hh;
#pragma unroll
                for (int j = 0; j < 6; j++)
                    acc[j] = fmaf(xv.x, w3s[h * C_OUT + c0 + j], acc[j]);
#pragma unroll
                for (int j = 0; j < 6; j++)
                    acc[j] = fmaf(xv.y, w3s[(h + 1) * C_OUT + c0 + j], acc[j]);
            }
            int p = p0 + pl;
            bool valid = p < N_PTS;
            if (valid) {
#pragma unroll
                for (int j = 0; j < 6; j++) y3[(size_t)p * C_OUT + c0 + j] = acc[j];
            }
            float s[6], q[6];
#pragma unroll
            for (int j = 0; j < 6; j++) {
                s[j] = valid ? acc[j] : 0.f;
                q[j] = s[j] * s[j];
            }
#pragma unroll
            for (int off = 32; off > 0; off >>= 1) {
#pragma unroll
                for (int j = 0; j < 6; j++) {
                    s[j] += __shfl_down(s[j], off);
                    q[j] += __shfl_down(q[j], off);
                }
            }
            if (pl == 0) {
#pragma unroll
                for (int j = 0; j < 6; j++) {
                    atomicAdd(&ssum[c0 + j], s[j]);
                    atomicAdd(&ssq[c0 + j], q[j]);
                }
            }
            __syncthreads();   // ssum flushed below + xs reuse next tile
        }
        if (bid < nTiles && t < C_OUT) {
            atomicAdd(&ws[SUM3_O + t], ssum[t]);
            atomicAdd(&ws[SQ3_O + t], ssq[t]);
        }
    }
    gg.sync();

    // ---- phase 5: out = bn3(y3) + feats ----
    {
        float* scs = (float*)smem;           // 24 f
        float* shs = (float*)(smem + 128);   // 24 f (16B aligned)
        if (t < C_OUT) {
            const float invN = 1.f / (float)N_PTS;
            float mean = ws[SUM3_O + t] * invN;
            float var = ws[SQ3_O + t] * invN - mean * mean;
            float s = g3[t] * rsqrtf(var + EPSV);
            scs[t] = s;
            shs[t] = b3[t] - mean * s;
        }
        __syncthreads();
        const float4* y3v = (const float4*)(ws + Y3F_O);
        const float4* fv = (const float4*)feats;
        float4* ov = (float4*)out;
        const int T = N_PTS * G4_OUT;
        for (int e = bid * 256 + t; e < T; e += nB * 256) {
            int g = e % G4_OUT;
            float4 y = y3v[e];
            float4 s = ((const float4*)scs)[g];
            float4 b = ((const float4*)shs)[g];
            float4 f = fv[e];
            ov[e] = f4_add(f4_fma4(y, s, b), f);
        }
    }
}

extern "C" void kernel_launch(void* const* d_in, const int* in_sizes, int n_in,
                              void* d_out, int out_size, void* d_ws, size_t ws_size,
                              hipStream_t stream) {
    const float* feats = (const float*)d_in[0];
    const float* w1 = (const float*)d_in[1];
    const float* g1 = (const float*)d_in[2];
    const float* b1 = (const float*)d_in[3];
    const float* w2 = (const float*)d_in[4];
    const float* g2 = (const float*)d_in[5];
    const float* b2 = (const float*)d_in[6];
    const float* w3 = (const float*)d_in[7];
    const float* g3 = (const float*)d_in[8];
    const float* b3 = (const float*)d_in[9];
    const int* in_idx = (const int*)d_in[10];
    float* ws = (float*)d_ws;
    float* out = (float*)d_out;

    void* args[] = {
        (void*)&feats, (void*)&w1, (void*)&g1, (void*)&b1, (void*)&w2,
        (void*)&g2, (void*)&b2, (void*)&w3, (void*)&g3, (void*)&b3,
        (void*)&in_idx, (void*)&ws, (void*)&out};

    int maxB = 2;  // conservative fallback if query fails
    hipOccupancyMaxActiveBlocksPerMultiprocessor(&maxB, (const void*)k_fused, 256, 0);
    if (maxB < 1) maxB = 1;
    int grid = maxB * 256;          // 256 CUs on MI355X
    if (grid > 2048) grid = 2048;
    hipLaunchCooperativeKernel((const void*)k_fused, dim3(grid), dim3(256),
                               args, 0, stream);
}

// Round 6
// 299.397 us; speedup vs baseline: 1.6728x; 1.6728x over previous
//
#include <hip/hip_runtime.h>
#include <hip/hip_fp16.h>

#define N_PTS 100000
#define KSZ 9
#define C_IN 24
#define C_HID 144
#define C_OUT 24
#define G4_HID 36   // C_HID/4
#define G8_HID 18   // C_HID/8
#define G4_OUT 6    // C_OUT/4
#define EPSV 1e-5f

// ---- workspace layout (bytes) ----
// y1h fp16 N*144 @0 | x2h fp16 N*144 @28.8M | y3 f32 N*24 @57.6M | stats @67.2M
#define X2H_B     28800000
#define Y3F_O     14400000       // float index of y3
#define ST_O      16800000       // float index of stats
#define ST_B      67200000
#define SUM1_O    (ST_O + 0)     // 144
#define SQ1_O     (ST_O + 160)   // 144
#define SUM2_O    (ST_O + 320)   // 144
#define SQ2_O     (ST_O + 480)   // 144
#define SUM3_O    (ST_O + 640)   // 24
#define SQ3_O     (ST_O + 672)   // 24

__device__ inline float4 f4z() { return make_float4(0.f, 0.f, 0.f, 0.f); }
__device__ inline float4 f4_add(float4 a, float4 b) {
    return make_float4(a.x + b.x, a.y + b.y, a.z + b.z, a.w + b.w);
}
__device__ inline float4 f4_fma4(float4 a, float4 b, float4 c) {
    return make_float4(fmaf(a.x, b.x, c.x), fmaf(a.y, b.y, c.y),
                       fmaf(a.z, b.z, c.z), fmaf(a.w, b.w, c.w));
}
__device__ inline float4 f4_fma_s(float s, float4 b, float4 c) {
    return make_float4(fmaf(s, b.x, c.x), fmaf(s, b.y, c.y),
                       fmaf(s, b.z, c.z), fmaf(s, b.w, c.w));
}
__device__ inline float4 f4_clamp6(float4 a) {
    return make_float4(fminf(fmaxf(a.x, 0.f), 6.f), fminf(fmaxf(a.y, 0.f), 6.f),
                       fminf(fmaxf(a.z, 0.f), 6.f), fminf(fmaxf(a.w, 0.f), 6.f));
}
__device__ inline unsigned pack2(float a, float b) {
    __half2 h = __floats2half2_rn(a, b);
    return *reinterpret_cast<unsigned*>(&h);
}
__device__ inline float2 uph(unsigned u) {
    __half2 h = *reinterpret_cast<__half2*>(&u);
    return __half22float2(h);
}

// ---- K1: GEMM1 raw: y1 = feats@w1 -> y1h fp16, accumulate SUM1/SQ1 (exact f32)
// 64-pt tile; wave-uniform w1 reads (broadcast); LDS f32 transpose for
// coalesced fp16 stores + fixed-channel stats.
__global__ __launch_bounds__(256) void k_gemm1(const float* __restrict__ feats,
                                               const float* __restrict__ w1,
                                               float* __restrict__ ws) {
    __shared__ __align__(16) char smem[38272];
    float*  xs   = (float*)smem;             // [64*25]  compute phase
    float4* w1s  = (float4*)(smem + 6400);   // [864]    compute phase
    float*  tile = (float*)smem;             // [64*145] repack phase (aliases)
    float*  lsum = (float*)(smem + 37120);   // [144]
    float*  lsq  = (float*)(smem + 37696);   // [144]
    const int t = threadIdx.x;
    const int p0 = blockIdx.x * 64;
    for (int e = t; e < C_IN * G4_HID; e += 256) w1s[e] = ((const float4*)w1)[e];
    for (int e = t; e < 64 * C_IN; e += 256) {
        int r = e / C_IN, c = e % C_IN;
        int p = p0 + r;
        xs[r * 25 + c] = (p < N_PTS) ? feats[(size_t)p * C_IN + c] : 0.f;
    }
    if (t < C_HID) { lsum[t] = 0.f; lsq[t] = 0.f; }
    __syncthreads();
    const int pt = t & 63;
    const int cg = __builtin_amdgcn_readfirstlane(t >> 6);  // wave-uniform
    float4 acc[9];
#pragma unroll
    for (int j = 0; j < 9; j++) acc[j] = f4z();
    for (int k = 0; k < C_IN; k++) {
        float xk = xs[pt * 25 + k];               // conflict-free (stride 25)
        const float4* wr = &w1s[k * G4_HID + cg * 9];  // wave-uniform -> broadcast
#pragma unroll
        for (int j = 0; j < 9; j++) acc[j] = f4_fma_s(xk, wr[j], acc[j]);
    }
    __syncthreads();  // xs/w1s dead; reuse as tile
    {
        float* dst = tile + pt * 145 + cg * 36;   // stride 145: scalar writes conflict-free
#pragma unroll
        for (int j = 0; j < 9; j++) {
            dst[4 * j + 0] = acc[j].x; dst[4 * j + 1] = acc[j].y;
            dst[4 * j + 2] = acc[j].z; dst[4 * j + 3] = acc[j].w;
        }
    }
    __syncthreads();
    // repack: fixed 8-channel group per thread -> fp16 store + register stats
    uint4* y1u = (uint4*)ws;
    bool active = t < 252;
    int g = t % G8_HID, r0 = t / G8_HID;
    float4 rsA = f4z(), rsB = f4z(), rqA = f4z(), rqB = f4z();
    if (active) {
        for (int r = r0; r < 64; r += 14) {
            int p = p0 + r;
            if (p >= N_PTS) break;
            const float* src = tile + r * 145 + 8 * g;
            float v0 = src[0], v1 = src[1], v2 = src[2], v3 = src[3];
            float v4 = src[4], v5 = src[5], v6 = src[6], v7 = src[7];
            uint4 o;
            o.x = pack2(v0, v1); o.y = pack2(v2, v3);
            o.z = pack2(v4, v5); o.w = pack2(v6, v7);
            y1u[(size_t)p * G8_HID + g] = o;
            float4 aA = make_float4(v0, v1, v2, v3), aB = make_float4(v4, v5, v6, v7);
            rsA = f4_add(rsA, aA); rsB = f4_add(rsB, aB);
            rqA = f4_fma4(aA, aA, rqA); rqB = f4_fma4(aB, aB, rqB);
        }
        int c0 = 8 * g;
        atomicAdd(&lsum[c0 + 0], rsA.x); atomicAdd(&lsum[c0 + 1], rsA.y);
        atomicAdd(&lsum[c0 + 2], rsA.z); atomicAdd(&lsum[c0 + 3], rsA.w);
        atomicAdd(&lsum[c0 + 4], rsB.x); atomicAdd(&lsum[c0 + 5], rsB.y);
        atomicAdd(&lsum[c0 + 6], rsB.z); atomicAdd(&lsum[c0 + 7], rsB.w);
        atomicAdd(&lsq[c0 + 0], rqA.x);  atomicAdd(&lsq[c0 + 1], rqA.y);
        atomicAdd(&lsq[c0 + 2], rqA.z);  atomicAdd(&lsq[c0 + 3], rqA.w);
        atomicAdd(&lsq[c0 + 4], rqB.x);  atomicAdd(&lsq[c0 + 5], rqB.y);
        atomicAdd(&lsq[c0 + 6], rqB.z);  atomicAdd(&lsq[c0 + 7], rqB.w);
    }
    __syncthreads();
    if (t < C_HID) {
        atomicAdd(&ws[SUM1_O + t], lsum[t]);
        atomicAdd(&ws[SQ1_O + t], lsq[t]);
    }
}

// ---- K2: gated 3x3 channelwise conv; BN1+relu6 applied to gathered values.
// ~75% of in_idx entries are the sentinel (N) -> gate skips those gathers.
__global__ __launch_bounds__(256) void k_conv(const float* __restrict__ w2,
                                              const float* __restrict__ g1,
                                              const float* __restrict__ b1,
                                              const int* __restrict__ in_idx,
                                              float* __restrict__ ws) {
    __shared__ float4 w2s[KSZ * G4_HID];    // 5184 B
    __shared__ float sc1L[C_HID], sh1L[C_HID];
    __shared__ float lsum[C_HID], lsq[C_HID];
    const int t = threadIdx.x;
    for (int e = t; e < KSZ * G4_HID; e += 256) w2s[e] = ((const float4*)w2)[e];
    if (t < C_HID) {
        const float invN = 1.f / (float)N_PTS;
        float mean = ws[SUM1_O + t] * invN;
        float var = ws[SQ1_O + t] * invN - mean * mean;
        float s = g1[t] * rsqrtf(var + EPSV);
        sc1L[t] = s;
        sh1L[t] = b1[t] - mean * s;
        lsum[t] = 0.f; lsq[t] = 0.f;
    }
    __syncthreads();
    const uint4* y1u = (const uint4*)ws;
    uint4* x2u = (uint4*)((char*)ws + X2H_B);
    bool active = t < 252;
    int pt = t / G8_HID, g = t % G8_HID;   // 14 points x 18 lane-groups
    float4 scA = ((const float4*)sc1L)[2 * g], scB = ((const float4*)sc1L)[2 * g + 1];
    float4 shA = ((const float4*)sh1L)[2 * g], shB = ((const float4*)sh1L)[2 * g + 1];
    float4 rsA = f4z(), rsB = f4z(), rqA = f4z(), rqB = f4z();
    const int nChunks = (N_PTS + 13) / 14;
    for (int ch = blockIdx.x; ch < nChunks; ch += gridDim.x) {
        int p = ch * 14 + pt;
        if (active && p < N_PTS) {
            int idx[KSZ];
#pragma unroll
            for (int k = 0; k < KSZ; k++) idx[k] = in_idx[k * N_PTS + p];
            float4 aA = f4z(), aB = f4z();
#pragma unroll
            for (int k = 0; k < KSZ; k++) {
                if (idx[k] < N_PTS) {   // skip sentinel: no gather, zero contribution
                    uint4 v = y1u[(size_t)idx[k] * G8_HID + g];
                    float2 f0 = uph(v.x), f1 = uph(v.y), f2 = uph(v.z), f3 = uph(v.w);
                    float4 vA = f4_clamp6(f4_fma4(make_float4(f0.x, f0.y, f1.x, f1.y), scA, shA));
                    float4 vB = f4_clamp6(f4_fma4(make_float4(f2.x, f2.y, f3.x, f3.y), scB, shB));
                    aA = f4_fma4(w2s[k * G4_HID + 2 * g], vA, aA);
                    aB = f4_fma4(w2s[k * G4_HID + 2 * g + 1], vB, aB);
                }
            }
            uint4 o;
            o.x = pack2(aA.x, aA.y); o.y = pack2(aA.z, aA.w);
            o.z = pack2(aB.x, aB.y); o.w = pack2(aB.z, aB.w);
            x2u[(size_t)p * G8_HID + g] = o;
            rsA = f4_add(rsA, aA); rsB = f4_add(rsB, aB);
            rqA = f4_fma4(aA, aA, rqA); rqB = f4_fma4(aB, aB, rqB);
        }
    }
    if (active) {
        int c0 = 8 * g;
        atomicAdd(&lsum[c0 + 0], rsA.x); atomicAdd(&lsum[c0 + 1], rsA.y);
        atomicAdd(&lsum[c0 + 2], rsA.z); atomicAdd(&lsum[c0 + 3], rsA.w);
        atomicAdd(&lsum[c0 + 4], rsB.x); atomicAdd(&lsum[c0 + 5], rsB.y);
        atomicAdd(&lsum[c0 + 6], rsB.z); atomicAdd(&lsum[c0 + 7], rsB.w);
        atomicAdd(&lsq[c0 + 0], rqA.x);  atomicAdd(&lsq[c0 + 1], rqA.y);
        atomicAdd(&lsq[c0 + 2], rqA.z);  atomicAdd(&lsq[c0 + 3], rqA.w);
        atomicAdd(&lsq[c0 + 4], rqB.x);  atomicAdd(&lsq[c0 + 5], rqB.y);
        atomicAdd(&lsq[c0 + 6], rqB.z);  atomicAdd(&lsq[c0 + 7], rqB.w);
    }
    __syncthreads();
    if (t < C_HID) {
        atomicAdd(&ws[SUM2_O + t], lsum[t]);
        atomicAdd(&ws[SQ2_O + t], lsq[t]);
    }
}

// ---- K3: GEMM2 with in-block BN2 finalize (bn2+relu6 on the fly) -> y3 + BN3 stats
#define TP 64
__global__ __launch_bounds__(256) void k_gemm2(const float* __restrict__ w3,
                                               const float* __restrict__ g2,
                                               const float* __restrict__ b2,
                                               float* __restrict__ ws) {
    __shared__ float xs[TP * 145];
    __shared__ float w3s[C_HID * C_OUT];
    __shared__ float sc2s[C_HID], sh2s[C_HID];
    __shared__ float ssum[C_OUT], ssq[C_OUT];
    const int t = threadIdx.x;
    for (int e = t; e < C_HID * C_OUT / 4; e += 256)
        ((float4*)w3s)[e] = ((const float4*)w3)[e];
    if (t < C_HID) {
        const float invN = 1.f / (float)N_PTS;
        float mean = ws[SUM2_O + t] * invN;
        float var = ws[SQ2_O + t] * invN - mean * mean;
        float s = g2[t] * rsqrtf(var + EPSV);
        sc2s[t] = s;
        sh2s[t] = b2[t] - mean * s;
    }
    if (t < C_OUT) { ssum[t] = 0.f; ssq[t] = 0.f; }
    __syncthreads();
    const uint4* x2u = (const uint4*)((char*)ws + X2H_B);
    int p0 = blockIdx.x * TP;
    for (int e = t; e < TP * G8_HID; e += 256) {
        int row = e / G8_HID, col = e % G8_HID;
        int p = p0 + row;
        int c0 = 8 * col;
        float v[8];
        if (p < N_PTS) {
            uint4 u = x2u[(size_t)p * G8_HID + col];
            float2 f0 = uph(u.x), f1 = uph(u.y), f2 = uph(u.z), f3 = uph(u.w);
            v[0] = f0.x; v[1] = f0.y; v[2] = f1.x; v[3] = f1.y;
            v[4] = f2.x; v[5] = f2.y; v[6] = f3.x; v[7] = f3.y;
#pragma unroll
            for (int i = 0; i < 8; i++)
                v[i] = fminf(fmaxf(fmaf(v[i], sc2s[c0 + i], sh2s[c0 + i]), 0.f), 6.f);
        } else {
#pragma unroll
            for (int i = 0; i < 8; i++) v[i] = 0.f;
        }
#pragma unroll
        for (int i = 0; i < 8; i++) xs[row * 145 + c0 + i] = v[i];
    }
    __syncthreads();
    int pl = t & 63, cgid = t >> 6;
    int c0 = 6 * cgid;
    float acc[6] = {0.f, 0.f, 0.f, 0.f, 0.f, 0.f};
    const float* xr = xs + pl * 145;
#pragma unroll 4
    for (int h = 0; h < C_HID; h++) {
        float x = xr[h];
#pragma unroll
        for (int j = 0; j < 6; j++) acc[j] = fmaf(x, w3s[h * C_OUT + c0 + j], acc[j]);
    }
    int p = p0 + pl;
    bool valid = p < N_PTS;
    float* y3 = ws + Y3F_O;
    if (valid) {
#pragma unroll
        for (int j = 0; j < 6; j++) y3[(size_t)p * C_OUT + c0 + j] = acc[j];
    }
    float s[6], q[6];
#pragma unroll
    for (int j = 0; j < 6; j++) {
        s[j] = valid ? acc[j] : 0.f;
        q[j] = s[j] * s[j];
    }
#pragma unroll
    for (int off = 32; off > 0; off >>= 1) {
#pragma unroll
        for (int j = 0; j < 6; j++) {
            s[j] += __shfl_down(s[j], off);
            q[j] += __shfl_down(q[j], off);
        }
    }
    if (pl == 0) {
#pragma unroll
        for (int j = 0; j < 6; j++) {
            atomicAdd(&ssum[c0 + j], s[j]);
            atomicAdd(&ssq[c0 + j], q[j]);
        }
    }
    __syncthreads();
    if (t < C_OUT) {
        atomicAdd(&ws[SUM3_O + t], ssum[t]);
        atomicAdd(&ws[SQ3_O + t], ssq[t]);
    }
}

// ---- K4: out = bn3(y3) + feats, with in-block BN3 finalize
__global__ __launch_bounds__(256) void k_out(const float* __restrict__ feats,
                                             const float* __restrict__ g3,
                                             const float* __restrict__ b3,
                                             const float* __restrict__ ws,
                                             float* __restrict__ out) {
    __shared__ float scs[32], shs[32];
    const int t = threadIdx.x;
    if (t < C_OUT) {
        const float invN = 1.f / (float)N_PTS;
        float mean = ws[SUM3_O + t] * invN;
        float var = ws[SQ3_O + t] * invN - mean * mean;
        float s = g3[t] * rsqrtf(var + EPSV);
        scs[t] = s;
        shs[t] = b3[t] - mean * s;
    }
    __syncthreads();
    int t4 = blockIdx.x * 256 + t;
    const int T = N_PTS * G4_OUT;
    if (t4 >= T) return;
    int g = t4 % G4_OUT;
    float4 y = ((const float4*)(ws + Y3F_O))[t4];
    float4 s = ((const float4*)scs)[g];
    float4 b = ((const float4*)shs)[g];
    float4 f = ((const float4*)feats)[t4];
    ((float4*)out)[t4] = f4_add(f4_fma4(y, s, b), f);
}

extern "C" void kernel_launch(void* const* d_in, const int* in_sizes, int n_in,
                              void* d_out, int out_size, void* d_ws, size_t ws_size,
                              hipStream_t stream) {
    const float* feats = (const float*)d_in[0];
    const float* w1 = (const float*)d_in[1];
    const float* g1 = (const float*)d_in[2];
    const float* b1 = (const float*)d_in[3];
    const float* w2 = (const float*)d_in[4];
    const float* g2 = (const float*)d_in[5];
    const float* b2 = (const float*)d_in[6];
    const float* w3 = (const float*)d_in[7];
    const float* g3 = (const float*)d_in[8];
    const float* b3 = (const float*)d_in[9];
    const int* in_idx = (const int*)d_in[10];
    float* ws = (float*)d_ws;
    float* out = (float*)d_out;

    hipMemsetAsync((char*)d_ws + ST_B, 0, 4096, stream);  // zero stat accumulators
    hipLaunchKernelGGL(k_gemm1, dim3((N_PTS + 63) / 64), dim3(256), 0, stream,
                       feats, w1, ws);
    hipLaunchKernelGGL(k_conv, dim3(2048), dim3(256), 0, stream,
                       w2, g1, b1, in_idx, ws);
    hipLaunchKernelGGL(k_gemm2, dim3((N_PTS + TP - 1) / TP), dim3(256), 0, stream,
                       w3, g2, b2, ws);
    hipLaunchKernelGGL(k_out, dim3((N_PTS * G4_OUT + 255) / 256), dim3(256), 0, stream,
                       feats, g3, b3, ws, out);
}